// Round 14
// baseline (98.386 us; speedup 1.0000x reference)
//
#include <hip/hip_runtime.h>
#include <math.h>

// Problem constants (from reference setup_inputs)
#define BS 32
#define CH 3
#define HH 512
#define WW 512
#define HWSZ (HH * WW)          // 262144
#define MOMENTUM 0.8
#define EPSILON 1e-5

// ---------------- stats kernel (symmetric + run-windowed) ----------------
// S1[c] = sum_b x[b,c,0,0]
// S2[c] = sum_{b,h,w} x^2
// S3[c] = sum_{b,h,w} x[h,w] * x[(-h)%H, (-w)%W]
//
// Per-f4 index math (verified r8..r10): for aligned f4 at o, partners of
// o+1..o+3 are .w,.z,.y of f4 at q1=(HWSZ+508-o)&mask; partner of o is .x
// of f4 at q2=(HWSZ+(w0?0:512)-o)&mask. For non-row-start f4s q2 == q1+4
// (no wrap, checked over all rows); only row-start f4s need the masked q2.
//
// Run structure (new): thread processes 4 CONSECUTIVE a-f4s (one 64B run,
// never crossing a row). q1(o_base+4k) = q1b-4k, so all partners live in
// the contiguous window W[i] = f4 at (q1b-12+4i), i=0..4, with
//   q1(k) = W[3-k],  q2(k) = W[4-k]   (k=0 row-start: W[4] := masked q2).
// Loads per 4 a-f4s: 4 + 5 = 9 (was 12). All windows verified in-plane.
//
// Symmetry accounting (verified r10): A-rows 0..255; rows>=1 factor 2 with
// partner-row s2 via sum(W[0..3]^2); row 0 factor 1, no partner-square;
// row 256 self-paired tail (factor 1) on blk 0. Every element counted once.

constexpr int BPP = 16;                  // 16-row bands, rows 0..255
constexpr int STAT_THREADS = 256;
constexpr int NBLOCKS = BS * CH * BPP;   // 1536
// band = 16 rows * 128 f4 = 2048 f4 = 512 runs of 4; 2 runs/thread

__global__ __launch_bounds__(STAT_THREADS) void stats_kernel(
    const float* __restrict__ x, double* __restrict__ sums) {
    const int plane = blockIdx.x / BPP;  // 0..95 = b*3+c
    const int blk   = blockIdx.x % BPP;
    const int c     = plane % CH;
    const float* __restrict__ base = x + (size_t)plane * HWSZ;
    const int tid = threadIdx.x;

    float s1 = 0.f, s2 = 0.f, s3 = 0.f;

    float4 A[2][4], W[2][5];
    int ob[2];

    // ---- batched loads: 2 runs x (4 a-f4 + 5 window-f4) = 18 in flight ----
#pragma unroll
    for (int n = 0; n < 2; ++n) {
        const int run    = n * STAT_THREADS + tid;        // 0..511
        const int o_base = blk * 8192 + run * 16;
        ob[n] = o_base;
        const bool w0run = (o_base & (WW - 1)) == 0;      // run starts a row
        const int q1b = (HWSZ + 508 - o_base) & (HWSZ - 1);
#pragma unroll
        for (int k = 0; k < 4; ++k)
            A[n][k] = *reinterpret_cast<const float4*>(base + o_base + 4 * k);
#pragma unroll
        for (int i = 0; i < 4; ++i)
            W[n][i] = *reinterpret_cast<const float4*>(base + q1b - 12 + 4 * i);
        const int q2a = w0run ? ((HWSZ - o_base) & (HWSZ - 1)) : (q1b + 4);
        W[n][4] = *reinterpret_cast<const float4*>(base + q2a);
    }

    // ---- consume ----
#pragma unroll
    for (int n = 0; n < 2; ++n) {
        const int o_base = ob[n];
        const int h = o_base >> 9;
        const float fpp = (h == 0) ? 0.f : 1.f;
        const float f3  = (h == 0) ? 1.f : 2.f;
        float asum = 0.f, qsum = 0.f, psum = 0.f;
#pragma unroll
        for (int k = 0; k < 4; ++k) {
            const float4 a  = A[n][k];
            const float4 q1 = W[n][3 - k];
            const float4 q2 = W[n][4 - k];
            asum += a.x * a.x + a.y * a.y + a.z * a.z + a.w * a.w;
            psum += a.x * q2.x + a.y * q1.w + a.z * q1.z + a.w * q1.y;
        }
#pragma unroll
        for (int i = 0; i < 4; ++i) {
            const float4 w = W[n][i];
            qsum += w.x * w.x + w.y * w.y + w.z * w.z + w.w * w.w;
        }
        s2 += asum + fpp * qsum;
        s3 += f3 * psum;
        if (o_base == 0) s1 += A[n][0].x;   // x[b,c,0,0]
    }

    // ---- row 256 tail (self-paired, factor 1) on blk 0, r10 verbatim ----
    if (blk == 0 && tid < 128) {
        const int o  = 256 * WW + tid * 4;
        const bool w0 = (tid == 0);
        const int q1 = (HWSZ + 508 - o) & (HWSZ - 1);
        const int q2 = (HWSZ + (w0 ? 0 : 512) - o) & (HWSZ - 1);
        const float4 a_  = *reinterpret_cast<const float4*>(base + o);
        const float4 p1_ = *reinterpret_cast<const float4*>(base + q1);
        const float4 p2_ = *reinterpret_cast<const float4*>(base + q2);
        s2 += a_.x * a_.x + a_.y * a_.y + a_.z * a_.z + a_.w * a_.w;
        s3 += a_.x * p2_.x + a_.y * p1_.w + a_.z * p1_.z + a_.w * p1_.y;
    }

    // ---- wave reduce, cross-wave via LDS, 3 double atomics per block ----
#pragma unroll
    for (int off = 32; off > 0; off >>= 1) {
        s1 += __shfl_down(s1, off);
        s2 += __shfl_down(s2, off);
        s3 += __shfl_down(s3, off);
    }
    __shared__ float red[3][4];
    const int lane = tid & 63, wv = tid >> 6;
    if (lane == 0) { red[0][wv] = s1; red[1][wv] = s2; red[2][wv] = s3; }
    __syncthreads();
    if (tid == 0) {
        double t1 = 0.0, t2 = 0.0, t3 = 0.0;
#pragma unroll
        for (int j = 0; j < 4; ++j) {
            t1 += (double)red[0][j];
            t2 += (double)red[1][j];
            t3 += (double)red[2][j];
        }
        atomicAdd(&sums[c * 3 + 0], t1);
        atomicAdd(&sums[c * 3 + 1], t2);
        atomicAdd(&sums[c * 3 + 2], t3);
    }
}

// ---------------- normalize (finalize folded in) ----------------
__global__ __launch_bounds__(256) void norm_kernel(
    const float* __restrict__ x, const double* __restrict__ sums,
    const float* __restrict__ gamma, const float* __restrict__ beta,
    const float* __restrict__ rmean, const float* __restrict__ rvar,
    float* __restrict__ out) {
    __shared__ float ssh[6];
    if (threadIdx.x < CH) {
        const int c = threadIdx.x;
        const double S1 = sums[c * 3 + 0];
        const double S2 = sums[c * 3 + 1];
        const double S3 = sums[c * 3 + 2];
        const double N = (double)BS * (double)HWSZ;
        const double mean = S1 / N;
        const double ex2  = (S2 + S3) / (2.0 * N * (double)HWSZ);
        const double var  = ex2 - mean * mean;
        const double rm = (double)rmean[c] * MOMENTUM + (1.0 - MOMENTUM) * mean;
        const double rv = (double)rvar[c]  * MOMENTUM + (1.0 - MOMENTUM) * var;
        const double inv_std = 1.0 / sqrt(rv + EPSILON);
        const float scale = (float)((double)gamma[c] * inv_std);
        const float shift = (float)((double)beta[c] - (double)scale * rm);
        ssh[c * 2 + 0] = scale;
        ssh[c * 2 + 1] = shift;
    }
    __syncthreads();
    float sc[CH], sh[CH];
#pragma unroll
    for (int c = 0; c < CH; ++c) { sc[c] = ssh[c * 2]; sh[c] = ssh[c * 2 + 1]; }
    const int n4 = BS * CH * HWSZ / 4;               // 6,291,456
    const int stride = gridDim.x * blockDim.x;
    for (int i4 = blockIdx.x * blockDim.x + threadIdx.x; i4 < n4; i4 += stride) {
        const int c = (i4 >> 16) % CH;               // 65536 f4 per plane
        const float4 v = reinterpret_cast<const float4*>(x)[i4];
        const float s = sc[c], t = sh[c];
        float4 o;
        o.x = fmaf(v.x, s, t);
        o.y = fmaf(v.y, s, t);
        o.z = fmaf(v.z, s, t);
        o.w = fmaf(v.w, s, t);
        reinterpret_cast<float4*>(out)[i4] = o;
    }
}

extern "C" void kernel_launch(void* const* d_in, const int* in_sizes, int n_in,
                              void* d_out, int out_size, void* d_ws, size_t ws_size,
                              hipStream_t stream) {
    const float* x     = (const float*)d_in[0];
    const float* gamma = (const float*)d_in[1];
    const float* beta  = (const float*)d_in[2];
    const float* rmean = (const float*)d_in[3];
    const float* rvar  = (const float*)d_in[4];
    float* out = (float*)d_out;

    double* sums = (double*)d_ws;                    // 9 doubles

    hipMemsetAsync(d_ws, 0, 80, stream);
    stats_kernel<<<NBLOCKS, STAT_THREADS, 0, stream>>>(x, sums);
    norm_kernel<<<2048, 256, 0, stream>>>(x, sums, gamma, beta, rmean, rvar, out);
}